// Round 4
// baseline (140.496 us; speedup 1.0000x reference)
//
#include <hip/hip_runtime.h>
#include <hip/hip_bf16.h>
#include <cstdint>
#include <cstddef>

#define SEQ   2048
#define BATCH 2
#define NROWS 4096          // BATCH*SEQ
#define EMB   1024
#define NHEAD 16
#define HD    64
#define QBLK  64
#define KVBLK 64

typedef __attribute__((ext_vector_type(8))) short bf16x8;
typedef __attribute__((ext_vector_type(4))) float f32x4;
typedef __hip_bfloat16 bf16_t;

__device__ __forceinline__ int swz(int row, int cb) { return cb ^ ((row & 7) << 4); }
__device__ __forceinline__ float max3f(float a, float b, float c) {
  return fmaxf(fmaxf(a, b), c);   // clang fuses to v_max3_f32
}

// ---------------- casts f32 -> bf16 (vectorized) ----------------
__global__ __launch_bounds__(256) void cast_f32_to_bf16(const float* __restrict__ in,
                                                        bf16_t* __restrict__ out, int n4) {
  int i = blockIdx.x * 256 + threadIdx.x;
  if (i >= n4) return;
  float4 v = reinterpret_cast<const float4*>(in)[i];
  union { ushort4 u; bf16_t h[4]; } o;
  o.h[0] = __float2bfloat16(v.x);
  o.h[1] = __float2bfloat16(v.y);
  o.h[2] = __float2bfloat16(v.z);
  o.h[3] = __float2bfloat16(v.w);
  reinterpret_cast<ushort4*>(out)[i] = o.u;
}

// 4 weight matrices in one launch (z selects)
__global__ __launch_bounds__(256) void cast4_w(const float* __restrict__ a,
                                               const float* __restrict__ b,
                                               const float* __restrict__ c,
                                               const float* __restrict__ d,
                                               bf16_t* __restrict__ oa, bf16_t* __restrict__ ob,
                                               bf16_t* __restrict__ oc, bf16_t* __restrict__ od,
                                               int n4) {
  const int z = blockIdx.z;
  const float* in = (z == 0) ? a : (z == 1) ? b : (z == 2) ? c : d;
  bf16_t* out = (z == 0) ? oa : (z == 1) ? ob : (z == 2) ? oc : od;
  int i = blockIdx.x * 256 + threadIdx.x;
  if (i >= n4) return;
  float4 v = reinterpret_cast<const float4*>(in)[i];
  union { ushort4 u; bf16_t h[4]; } o;
  o.h[0] = __float2bfloat16(v.x);
  o.h[1] = __float2bfloat16(v.y);
  o.h[2] = __float2bfloat16(v.z);
  o.h[3] = __float2bfloat16(v.w);
  reinterpret_cast<ushort4*>(out)[i] = o.u;
}

// ---------------- 128x128 bf16 MFMA GEMM (m97 structure) ----------------
// Y = A @ W^T, A [M][1024] bf16 row-major, W [N][1024] bf16 row-major.
// MODE 0: bf16 row-major out. MODE 1: f32 out = acc + Res. MODE 2: bf16 out
// written head-transposed: Vt[(row>>11)*1024 + col][row&2047].
template <int MODE>
__device__ __forceinline__ void gemm128_body(const bf16_t* __restrict__ A,
                                             const bf16_t* __restrict__ W,
                                             bf16_t* __restrict__ Ob,
                                             float* __restrict__ Of,
                                             const float* __restrict__ Res) {
  __shared__ __align__(16) bf16_t As[128 * 32];
  __shared__ __align__(16) bf16_t Bs[128 * 32];
  const int tid = threadIdx.x;
  const int lane = tid & 63;
  const int wv = tid >> 6;
  const int wm = wv >> 1, wn = wv & 1;          // 2x2 waves, each owns 64x64
  const int brow = blockIdx.y * 128;
  const int bcol = blockIdx.x * 128;
  const int lr = lane & 15, lg = lane >> 4;

  f32x4 acc[4][4] = {};

  auto* As3 = (__attribute__((address_space(3))) char*)As;
  auto* Bs3 = (__attribute__((address_space(3))) char*)Bs;

  for (int k0 = 0; k0 < EMB; k0 += 32) {
    __syncthreads();
#pragma unroll
    for (int i = 0; i < 2; ++i) {
      const int chunk = i * 256 + tid;          // 0..511, 16B each
      const int row = chunk >> 2;               // tile row 0..127
      const int kc = (chunk & 3) * 8;           // k element 0/8/16/24
      const bf16_t* ga = A + (size_t)(brow + row) * EMB + k0 + kc;
      const bf16_t* gb = W + (size_t)(bcol + row) * EMB + k0 + kc;
      __builtin_amdgcn_global_load_lds((const __attribute__((address_space(1))) void*)ga,
                                       (__attribute__((address_space(3))) void*)(As3 + chunk * 16),
                                       16, 0, 0);
      __builtin_amdgcn_global_load_lds((const __attribute__((address_space(1))) void*)gb,
                                       (__attribute__((address_space(3))) void*)(Bs3 + chunk * 16),
                                       16, 0, 0);
    }
    __syncthreads();

    bf16x8 af[4], bfr[4];
#pragma unroll
    for (int m = 0; m < 4; ++m)
      af[m] = *reinterpret_cast<const bf16x8*>(&As[(wm * 64 + m * 16 + lr) * 32 + lg * 8]);
#pragma unroll
    for (int n = 0; n < 4; ++n)
      bfr[n] = *reinterpret_cast<const bf16x8*>(&Bs[(wn * 64 + n * 16 + lr) * 32 + lg * 8]);
#pragma unroll
    for (int m = 0; m < 4; ++m)
#pragma unroll
      for (int n = 0; n < 4; ++n)
        acc[m][n] = __builtin_amdgcn_mfma_f32_16x16x32_bf16(af[m], bfr[n], acc[m][n], 0, 0, 0);
  }

  const int r0 = brow + wm * 64;
  const int c0 = bcol + wn * 64;
#pragma unroll
  for (int m = 0; m < 4; ++m)
#pragma unroll
    for (int n = 0; n < 4; ++n) {
      if (MODE == 2) {
        const int row0 = r0 + m * 16 + lg * 4;
        const int col = c0 + n * 16 + lr;
        const size_t vt_row = (size_t)(row0 >> 11) * 1024 + col;
        const int s = row0 & 2047;
        union { uint2 u2; bf16_t h[4]; } pu;
#pragma unroll
        for (int r = 0; r < 4; ++r) pu.h[r] = __float2bfloat16(acc[m][n][r]);
        *reinterpret_cast<uint2*>(Ob + vt_row * SEQ + s) = pu.u2;
      } else {
#pragma unroll
        for (int r = 0; r < 4; ++r) {
          const int row = r0 + m * 16 + lg * 4 + r;
          const int col = c0 + n * 16 + lr;
          const size_t idx = (size_t)row * EMB + col;
          if (MODE == 0) Ob[idx] = __float2bfloat16(acc[m][n][r]);
          else Of[idx] = acc[m][n][r] + Res[idx];
        }
      }
    }
}

__global__ __launch_bounds__(256) void gemm_qkv(const bf16_t* __restrict__ X,
                                                const bf16_t* __restrict__ Wq,
                                                const bf16_t* __restrict__ Wk,
                                                const bf16_t* __restrict__ Wv,
                                                bf16_t* __restrict__ Q,
                                                bf16_t* __restrict__ K,
                                                bf16_t* __restrict__ Vt) {
  if (blockIdx.z == 0)      gemm128_body<0>(X, Wq, Q, nullptr, nullptr);
  else if (blockIdx.z == 1) gemm128_body<0>(X, Wk, K, nullptr, nullptr);
  else                      gemm128_body<2>(X, Wv, Vt, nullptr, nullptr);
}

__global__ __launch_bounds__(256) void gemm_out(const bf16_t* __restrict__ Attn,
                                                const bf16_t* __restrict__ Wo,
                                                float* __restrict__ Y,
                                                const float* __restrict__ X) {
  gemm128_body<1>(Attn, Wo, nullptr, Y, X);
}

// ---------------- flash attention: 4 waves/block, swapped QK^T, exp2-domain ----------------
// K/V double-buffered (T14); defer-max (T13); setprio (T5); hoisted stage addrs;
// cvt_pk P-pack (T12); max3 tree (T17); pairwise denominators.
__global__ __launch_bounds__(256) void attn_kernel(const bf16_t* __restrict__ Q,
                                                   const bf16_t* __restrict__ K,
                                                   const bf16_t* __restrict__ Vt,
                                                   bf16_t* __restrict__ Oout) {
  __shared__ __align__(16) bf16_t Ks[2][KVBLK * 64];   // swizzled [j][d], 8KB each
  __shared__ __align__(16) bf16_t Vs[2][64 * KVBLK];   // swizzled [d][j], 8KB each
  __shared__ __align__(16) bf16_t Pl[4][16 * 64];      // per-wave P [q][j] swizzled

  const int tid = threadIdx.x;
  const int lane = tid & 63;
  const int wv = tid >> 6;
  const int lr = lane & 15, lg = lane >> 4;

  // XCD-aware bijective swizzle
  const int f = blockIdx.x + 32 * blockIdx.y + 512 * blockIdx.z;
  const int w = (f & 7) * 128 + (f >> 3);
  const int qb = w & 31;
  const int h = (w >> 5) & 15;
  const int b = w >> 9;

  const size_t baseRow = (size_t)b * SEQ;
  const int hoff = h * HD;
  const int q0 = qb * QBLK + wv * 16;

  // Q fragments, pre-scaled by 0.125*log2(e) -> softmax in exp2 domain
  const float qscale = 0.125f * 1.44269504f;
  bf16x8 qf[2];
#pragma unroll
  for (int kk = 0; kk < 2; ++kk) {
    bf16x8 t = *reinterpret_cast<const bf16x8*>(
        &Q[(baseRow + q0 + lr) * EMB + hoff + kk * 32 + lg * 8]);
    union { bf16x8 v; bf16_t h[8]; } u;
    u.v = t;
#pragma unroll
    for (int e = 0; e < 8; ++e)
      u.h[e] = __float2bfloat16(__bfloat162float(u.h[e]) * qscale);
    qf[kk] = u.v;
  }

  f32x4 o[4] = {};
  float mrow = -1e30f, lrow = 0.f;

  auto* Ks3 = (__attribute__((address_space(3))) char*)&Ks[0][0];
  auto* Vs3 = (__attribute__((address_space(3))) char*)&Vs[0][0];

  // hoisted per-thread staging pointers: row = tid>>3 (same row&7 for both chunks)
  const int srow = tid >> 3;
  const int scb = swz(srow, (tid & 7) * 16) >> 1;   // element offset within row
  const bf16_t* kp = K + (baseRow + srow) * EMB + hoff + scb;     // advances KVBLK*EMB/tile
  const bf16_t* vp = Vt + ((size_t)(b * 1024 + hoff) + srow) * SEQ + scb;  // advances KVBLK/tile

  auto stage = [&](int buf, const bf16_t* kpp, const bf16_t* vpp) {
#pragma unroll
    for (int i = 0; i < 2; ++i) {
      const int c = i * 256 + tid;
      __builtin_amdgcn_global_load_lds(
          (const __attribute__((address_space(1))) void*)(kpp + i * 32 * EMB),
          (__attribute__((address_space(3))) void*)(Ks3 + buf * 8192 + c * 16), 16, 0, 0);
      __builtin_amdgcn_global_load_lds(
          (const __attribute__((address_space(1))) void*)(vpp + i * 32 * SEQ),
          (__attribute__((address_space(3))) void*)(Vs3 + buf * 8192 + c * 16), 16, 0, 0);
    }
  };

  stage(0, kp, vp);
  kp += KVBLK * EMB;
  vp += KVBLK;
  __syncthreads();  // buf0 ready

  for (int it = 0; it < SEQ / KVBLK; ++it) {
    const int cur = it & 1;
    if (it + 1 < SEQ / KVBLK) {
      stage(cur ^ 1, kp, vp);   // async prefetch
      kp += KVBLK * EMB;
      vp += KVBLK;
    }

    const char* Kb = (const char*)Ks + cur * 8192;
    const char* Vb = (const char*)Vs + cur * 8192;

    // ---- S^T = K . Q^T : lane holds S^T[j = t*16+lg*4+r][q = lr] (log2 units) ----
    f32x4 st[4] = {};
    __builtin_amdgcn_s_setprio(1);
#pragma unroll
    for (int t = 0; t < 4; ++t) {
      const int row = t * 16 + lr;
#pragma unroll
      for (int kk = 0; kk < 2; ++kk) {
        bf16x8 kf = *reinterpret_cast<const bf16x8*>(Kb + row * 128 + swz(lr, kk * 64 + lg * 16));
        st[t] = __builtin_amdgcn_mfma_f32_16x16x32_bf16(kf, qf[kk], st[t], 0, 0, 0);
      }
    }
    __builtin_amdgcn_s_setprio(0);

    // ---- online softmax, exp2 domain; max via v_max3 tree ----
    const float m0 = max3f(st[0][0], st[0][1], st[0][2]);
    const float m1 = max3f(st[0][3], st[1][0], st[1][1]);
    const float m2 = max3f(st[1][2], st[1][3], st[2][0]);
    const float m3 = max3f(st[2][1], st[2][2], st[2][3]);
    const float m4 = max3f(st[3][0], st[3][1], st[3][2]);
    float mx = fmaxf(max3f(m0, m1, m2), max3f(m3, m4, st[3][3]));
    mx = fmaxf(mx, __shfl_xor(mx, 16));
    mx = fmaxf(mx, __shfl_xor(mx, 32));

    // defer-max: only rescale when the tile max grew by > 8 (p bounded by 2^8)
    if (!__all(mx - mrow <= 8.f)) {
      const float mnew = fmaxf(mrow, mx);
      const float al = __builtin_amdgcn_exp2f(mrow - mnew);
      mrow = mnew;
      lrow *= al;
#pragma unroll
      for (int t = 0; t < 4; ++t)
#pragma unroll
        for (int r = 0; r < 4; ++r) o[t][r] *= al;
    }

    // exp2 in place + pairwise partial sums
    float lsp[4];
#pragma unroll
    for (int t = 0; t < 4; ++t) {
#pragma unroll
      for (int r = 0; r < 4; ++r) st[t][r] = __builtin_amdgcn_exp2f(st[t][r] - mrow);
      lsp[t] = (st[t][0] + st[t][1]) + (st[t][2] + st[t][3]);
    }
    float ls = (lsp[0] + lsp[1]) + (lsp[2] + lsp[3]);
    ls += __shfl_xor(ls, 16);
    ls += __shfl_xor(ls, 32);
    lrow += ls;

    // ---- P -> LDS via v_cvt_pk_bf16_f32 (T12) ----
    char* Plw = (char*)&Pl[wv][0];
#pragma unroll
    for (int t = 0; t < 4; ++t) {
      uint32_t d0, d1;
      asm("v_cvt_pk_bf16_f32 %0, %1, %2" : "=v"(d0) : "v"(st[t][0]), "v"(st[t][1]));
      asm("v_cvt_pk_bf16_f32 %0, %1, %2" : "=v"(d1) : "v"(st[t][2]), "v"(st[t][3]));
      uint2 u2; u2.x = d0; u2.y = d1;
      *reinterpret_cast<uint2*>(Plw + lr * 128 + swz(lr, t * 32 + lg * 8)) = u2;
    }
    bf16x8 pf[2];
#pragma unroll
    for (int jt = 0; jt < 2; ++jt)
      pf[jt] = *reinterpret_cast<const bf16x8*>(Plw + lr * 128 + swz(lr, jt * 64 + lg * 16));

    // ---- O^T += Vt . P : lane accumulates O^T[d = t*16+lg*4+r][q = lr] ----
    __builtin_amdgcn_s_setprio(1);
#pragma unroll
    for (int t = 0; t < 4; ++t) {
      const int row = t * 16 + lr;
#pragma unroll
      for (int jt = 0; jt < 2; ++jt) {
        bf16x8 vf = *reinterpret_cast<const bf16x8*>(Vb + row * 128 + swz(lr, jt * 64 + lg * 16));
        o[t] = __builtin_amdgcn_mfma_f32_16x16x32_bf16(vf, pf[jt], o[t], 0, 0, 0);
      }
    }
    __builtin_amdgcn_s_setprio(0);

    __syncthreads();  // one barrier/tile: prefetched loads drained + buffers consumed
  }

  // ---- epilogue: lane owns q = lr, d = t*16+lg*4+r (4 consecutive -> uint2) ----
  const float inv = 1.f / lrow;
  const size_t orow = (baseRow + q0 + lr) * EMB + hoff;
#pragma unroll
  for (int t = 0; t < 4; ++t) {
    union { uint2 u2; bf16_t h[4]; } pu;
#pragma unroll
    for (int r = 0; r < 4; ++r) pu.h[r] = __float2bfloat16(o[t][r] * inv);
    *reinterpret_cast<uint2*>(Oout + orow + t * 16 + lg * 4) = pu.u2;
  }
}

// ---------------- row LayerNorm (1024 cols), f32 ----------------
__global__ __launch_bounds__(256) void ln_kernel(const float* __restrict__ Y,
                                                 const float* __restrict__ gamma,
                                                 const float* __restrict__ beta,
                                                 float* __restrict__ Out) {
  const int row = blockIdx.x;
  const int tid = threadIdx.x;
  const float4 v = reinterpret_cast<const float4*>(Y + (size_t)row * EMB)[tid];
  float s = v.x + v.y + v.z + v.w;
  float s2 = v.x * v.x + v.y * v.y + v.z * v.z + v.w * v.w;
#pragma unroll
  for (int m = 1; m < 64; m <<= 1) {
    s += __shfl_xor(s, m);
    s2 += __shfl_xor(s2, m);
  }
  __shared__ float ws[4], ws2[4];
  const int w = tid >> 6;
  if ((tid & 63) == 0) { ws[w] = s; ws2[w] = s2; }
  __syncthreads();
  s = ws[0] + ws[1] + ws[2] + ws[3];
  s2 = ws2[0] + ws2[1] + ws2[2] + ws2[3];
  const float mu = s * (1.f / EMB);
  const float var = s2 * (1.f / EMB) - mu * mu;
  const float rstd = rsqrtf(var + 1e-5f);
  const float4 g = reinterpret_cast<const float4*>(gamma)[tid];
  const float4 bt = reinterpret_cast<const float4*>(beta)[tid];
  float4 ov;
  ov.x = (v.x - mu) * rstd * g.x + bt.x;
  ov.y = (v.y - mu) * rstd * g.y + bt.y;
  ov.z = (v.z - mu) * rstd * g.z + bt.z;
  ov.w = (v.w - mu) * rstd * g.w + bt.w;
  reinterpret_cast<float4*>(Out + (size_t)row * EMB)[tid] = ov;
}

// ---------------- launch ----------------
extern "C" void kernel_launch(void* const* d_in, const int* in_sizes, int n_in,
                              void* d_out, int out_size, void* d_ws, size_t ws_size,
                              hipStream_t stream) {
  const float* x = (const float*)d_in[0];
  const float* Wq = (const float*)d_in[1];
  const float* Wk = (const float*)d_in[2];
  const float* Wv = (const float*)d_in[3];
  const float* Wo = (const float*)d_in[4];
  const float* gamma = (const float*)d_in[5];
  const float* beta = (const float*)d_in[6];
  float* out = (float*)d_out;

  char* p = (char*)d_ws;
  const size_t sz_rows_bf = (size_t)NROWS * EMB * sizeof(bf16_t);  // 8 MB
  const size_t sz_w_bf = (size_t)EMB * EMB * sizeof(bf16_t);       // 2 MB
  bf16_t* xb = (bf16_t*)p; p += sz_rows_bf;
  bf16_t* wqb = (bf16_t*)p; p += sz_w_bf;
  bf16_t* wkb = (bf16_t*)p; p += sz_w_bf;
  bf16_t* wvb = (bf16_t*)p; p += sz_w_bf;
  bf16_t* wob = (bf16_t*)p; p += sz_w_bf;
  bf16_t* q = (bf16_t*)p; p += sz_rows_bf;
  bf16_t* k = (bf16_t*)p; p += sz_rows_bf;
  bf16_t* vt = (bf16_t*)p; p += sz_rows_bf;   // [B*H*D][S] = 2048 x 2048
  bf16_t* attn = (bf16_t*)p; p += sz_rows_bf;
  float* y = (float*)q;  // alias: q/k dead after attn_kernel; y (16MB) = q+k

  const int n4x = NROWS * EMB / 4;
  const int n4w = EMB * EMB / 4;
  cast_f32_to_bf16<<<n4x / 256, 256, 0, stream>>>(x, xb, n4x);
  cast4_w<<<dim3(n4w / 256, 1, 4), 256, 0, stream>>>(Wq, Wk, Wv, Wo, wqb, wkb, wvb, wob, n4w);

  gemm_qkv<<<dim3(EMB / 128, NROWS / 128, 3), 256, 0, stream>>>(xb, wqb, wkb, wvb, q, k, vt);

  attn_kernel<<<dim3(SEQ / QBLK, NHEAD, BATCH), 256, 0, stream>>>(q, k, vt, attn);

  gemm_out<<<dim3(EMB / 128, NROWS / 128, 1), 256, 0, stream>>>(attn, wob, y, x);

  ln_kernel<<<NROWS, 256, 0, stream>>>(y, gamma, beta, out);
}

// Round 5
// 133.929 us; speedup vs baseline: 1.0490x; 1.0490x over previous
//
#include <hip/hip_runtime.h>
#include <hip/hip_bf16.h>
#include <cstdint>
#include <cstddef>

#define SEQ   2048
#define BATCH 2
#define NROWS 4096          // BATCH*SEQ
#define EMB   1024
#define NHEAD 16
#define HD    64
#define KVBLK 64

typedef __attribute__((ext_vector_type(8))) short bf16x8;
typedef __attribute__((ext_vector_type(4))) float f32x4;
typedef __attribute__((ext_vector_type(16))) float f32x16;
typedef __attribute__((ext_vector_type(2))) int i32x2;
typedef __hip_bfloat16 bf16_t;

__device__ __forceinline__ int swz(int row, int cb) { return cb ^ ((row & 7) << 4); }

// permlane32_swap: ra = {a_lo, b_lo(from lane-32)}, rb = {a_hi(from lane+32), b_hi}
__device__ __forceinline__ void plswap(int a, int b, int& ra, int& rb) {
#if __has_builtin(__builtin_amdgcn_permlane32_swap)
  i32x2 r = __builtin_amdgcn_permlane32_swap(a, b, false, false);
  ra = r[0]; rb = r[1];
#else
  const int pa = __shfl_xor(a, 32), pb = __shfl_xor(b, 32);
  const bool lo = (threadIdx.x & 63) < 32;
  ra = lo ? a : pb;
  rb = lo ? pa : b;
#endif
}
__device__ __forceinline__ float pairmax32(float v) {
  int r0, r1;
  plswap(__float_as_int(v), __float_as_int(v), r0, r1);
  return fmaxf(__int_as_float(r0), __int_as_float(r1));
}
__device__ __forceinline__ float pairsum32(float v) {
  int r0, r1;
  plswap(__float_as_int(v), __float_as_int(v), r0, r1);
  return __int_as_float(r0) + __int_as_float(r1);
}

// ---------------- casts f32 -> bf16 (vectorized) ----------------
__global__ __launch_bounds__(256) void cast_f32_to_bf16(const float* __restrict__ in,
                                                        bf16_t* __restrict__ out, int n4) {
  int i = blockIdx.x * 256 + threadIdx.x;
  if (i >= n4) return;
  float4 v = reinterpret_cast<const float4*>(in)[i];
  union { ushort4 u; bf16_t h[4]; } o;
  o.h[0] = __float2bfloat16(v.x);
  o.h[1] = __float2bfloat16(v.y);
  o.h[2] = __float2bfloat16(v.z);
  o.h[3] = __float2bfloat16(v.w);
  reinterpret_cast<ushort4*>(out)[i] = o.u;
}

__global__ __launch_bounds__(256) void cast4_w(const float* __restrict__ a,
                                               const float* __restrict__ b,
                                               const float* __restrict__ c,
                                               const float* __restrict__ d,
                                               bf16_t* __restrict__ oa, bf16_t* __restrict__ ob,
                                               bf16_t* __restrict__ oc, bf16_t* __restrict__ od,
                                               int n4) {
  const int z = blockIdx.z;
  const float* in = (z == 0) ? a : (z == 1) ? b : (z == 2) ? c : d;
  bf16_t* out = (z == 0) ? oa : (z == 1) ? ob : (z == 2) ? oc : od;
  int i = blockIdx.x * 256 + threadIdx.x;
  if (i >= n4) return;
  float4 v = reinterpret_cast<const float4*>(in)[i];
  union { ushort4 u; bf16_t h[4]; } o;
  o.h[0] = __float2bfloat16(v.x);
  o.h[1] = __float2bfloat16(v.y);
  o.h[2] = __float2bfloat16(v.z);
  o.h[3] = __float2bfloat16(v.w);
  reinterpret_cast<ushort4*>(out)[i] = o.u;
}

// ---------------- 128x128 bf16 MFMA GEMM (m97 structure) ----------------
template <int MODE>
__device__ __forceinline__ void gemm128_body(const bf16_t* __restrict__ A,
                                             const bf16_t* __restrict__ W,
                                             bf16_t* __restrict__ Ob,
                                             float* __restrict__ Of,
                                             const float* __restrict__ Res) {
  __shared__ __align__(16) bf16_t As[128 * 32];
  __shared__ __align__(16) bf16_t Bs[128 * 32];
  const int tid = threadIdx.x;
  const int lane = tid & 63;
  const int wv = tid >> 6;
  const int wm = wv >> 1, wn = wv & 1;          // 2x2 waves, each owns 64x64
  const int brow = blockIdx.y * 128;
  const int bcol = blockIdx.x * 128;
  const int lr = lane & 15, lg = lane >> 4;

  f32x4 acc[4][4] = {};

  auto* As3 = (__attribute__((address_space(3))) char*)As;
  auto* Bs3 = (__attribute__((address_space(3))) char*)Bs;

  for (int k0 = 0; k0 < EMB; k0 += 32) {
    __syncthreads();
#pragma unroll
    for (int i = 0; i < 2; ++i) {
      const int chunk = i * 256 + tid;          // 0..511, 16B each
      const int row = chunk >> 2;               // tile row 0..127
      const int kc = (chunk & 3) * 8;           // k element 0/8/16/24
      const bf16_t* ga = A + (size_t)(brow + row) * EMB + k0 + kc;
      const bf16_t* gb = W + (size_t)(bcol + row) * EMB + k0 + kc;
      __builtin_amdgcn_global_load_lds((const __attribute__((address_space(1))) void*)ga,
                                       (__attribute__((address_space(3))) void*)(As3 + chunk * 16),
                                       16, 0, 0);
      __builtin_amdgcn_global_load_lds((const __attribute__((address_space(1))) void*)gb,
                                       (__attribute__((address_space(3))) void*)(Bs3 + chunk * 16),
                                       16, 0, 0);
    }
    __syncthreads();

    bf16x8 af[4], bfr[4];
#pragma unroll
    for (int m = 0; m < 4; ++m)
      af[m] = *reinterpret_cast<const bf16x8*>(&As[(wm * 64 + m * 16 + lr) * 32 + lg * 8]);
#pragma unroll
    for (int n = 0; n < 4; ++n)
      bfr[n] = *reinterpret_cast<const bf16x8*>(&Bs[(wn * 64 + n * 16 + lr) * 32 + lg * 8]);
#pragma unroll
    for (int m = 0; m < 4; ++m)
#pragma unroll
      for (int n = 0; n < 4; ++n)
        acc[m][n] = __builtin_amdgcn_mfma_f32_16x16x32_bf16(af[m], bfr[n], acc[m][n], 0, 0, 0);
  }

  const int r0 = brow + wm * 64;
  const int c0 = bcol + wn * 64;
#pragma unroll
  for (int m = 0; m < 4; ++m)
#pragma unroll
    for (int n = 0; n < 4; ++n) {
      if (MODE == 2) {
        const int row0 = r0 + m * 16 + lg * 4;
        const int col = c0 + n * 16 + lr;
        const size_t vt_row = (size_t)(row0 >> 11) * 1024 + col;
        const int s = row0 & 2047;
        union { uint2 u2; bf16_t h[4]; } pu;
#pragma unroll
        for (int r = 0; r < 4; ++r) pu.h[r] = __float2bfloat16(acc[m][n][r]);
        *reinterpret_cast<uint2*>(Ob + vt_row * SEQ + s) = pu.u2;
      } else {
#pragma unroll
        for (int r = 0; r < 4; ++r) {
          const int row = r0 + m * 16 + lg * 4 + r;
          const int col = c0 + n * 16 + lr;
          const size_t idx = (size_t)row * EMB + col;
          if (MODE == 0) Ob[idx] = __float2bfloat16(acc[m][n][r]);
          else Of[idx] = acc[m][n][r] + Res[idx];
        }
      }
    }
}

__global__ __launch_bounds__(256) void gemm_qkv(const bf16_t* __restrict__ X,
                                                const bf16_t* __restrict__ Wq,
                                                const bf16_t* __restrict__ Wk,
                                                const bf16_t* __restrict__ Wv,
                                                bf16_t* __restrict__ Q,
                                                bf16_t* __restrict__ K,
                                                bf16_t* __restrict__ Vt) {
  if (blockIdx.z == 0)      gemm128_body<0>(X, Wq, Q, nullptr, nullptr);
  else if (blockIdx.z == 1) gemm128_body<0>(X, Wk, K, nullptr, nullptr);
  else                      gemm128_body<2>(X, Wv, Vt, nullptr, nullptr);
}

__global__ __launch_bounds__(256) void gemm_out(const bf16_t* __restrict__ Attn,
                                                const bf16_t* __restrict__ Wo,
                                                float* __restrict__ Y,
                                                const float* __restrict__ X) {
  gemm128_body<1>(Attn, Wo, nullptr, Y, X);
}

// ---------------- flash attention: 32x32 MFMA, in-register P (m214 structure) ----
// 4 waves x 32 q-rows; swapped QK^T; softmax + P->B-frag fully in-register
// (cvt_pk + permlane32_swap); K/V dbuf via global_load_lds; defer-max; exp2 domain.
__global__ __launch_bounds__(256) void attn_kernel(const bf16_t* __restrict__ Q,
                                                   const bf16_t* __restrict__ K,
                                                   const bf16_t* __restrict__ Vt,
                                                   bf16_t* __restrict__ Oout) {
  __shared__ __align__(16) bf16_t Ks[2][KVBLK * 64];   // swizzled [j][d], 8KB each
  __shared__ __align__(16) bf16_t Vs[2][64 * KVBLK];   // swizzled [d][j], 8KB each

  const int tid = threadIdx.x;
  const int lane = tid & 63;
  const int wv = tid >> 6;
  const int lq = lane & 31;     // q column / A row
  const int lh = lane >> 5;     // k-group half

  // XCD-aware bijective swizzle over 512 blocks
  const int f = blockIdx.x + 16 * blockIdx.y + 256 * blockIdx.z;
  const int w = (f & 7) * 64 + (f >> 3);
  const int qb = w & 15;
  const int h = (w >> 4) & 15;
  const int b = w >> 8;

  const size_t baseRow = (size_t)b * SEQ;
  const int hoff = h * HD;
  const int q0 = qb * 128 + wv * 32;

  // Q B-frags: col q = lq, d = ks*16 + lh*8 + e; pre-scaled by 0.125*log2(e)
  const float qscale = 0.125f * 1.44269504f;
  bf16x8 qf[4];
#pragma unroll
  for (int ks = 0; ks < 4; ++ks) {
    bf16x8 t = *reinterpret_cast<const bf16x8*>(
        &Q[(baseRow + q0 + lq) * EMB + hoff + ks * 16 + lh * 8]);
    union { bf16x8 v; bf16_t h[8]; } u;
    u.v = t;
#pragma unroll
    for (int e = 0; e < 8; ++e)
      u.h[e] = __float2bfloat16(__bfloat162float(u.h[e]) * qscale);
    qf[ks] = u.v;
  }

  f32x16 o[2] = {};
  float mrow = -1e30f, lrow = 0.f;

  auto* Ks3 = (__attribute__((address_space(3))) char*)&Ks[0][0];
  auto* Vs3 = (__attribute__((address_space(3))) char*)&Vs[0][0];

  // hoisted per-thread staging pointers (row = tid>>3; same row&7 both chunks)
  const int srow = tid >> 3;
  const int scb = swz(srow, (tid & 7) * 16) >> 1;
  const bf16_t* kp = K + (baseRow + srow) * EMB + hoff + scb;
  const bf16_t* vp = Vt + ((size_t)(b * 1024 + hoff) + srow) * SEQ + scb;

  auto stage = [&](int buf, const bf16_t* kpp, const bf16_t* vpp) {
#pragma unroll
    for (int i = 0; i < 2; ++i) {
      const int c = i * 256 + tid;
      __builtin_amdgcn_global_load_lds(
          (const __attribute__((address_space(1))) void*)(kpp + i * 32 * EMB),
          (__attribute__((address_space(3))) void*)(Ks3 + buf * 8192 + c * 16), 16, 0, 0);
      __builtin_amdgcn_global_load_lds(
          (const __attribute__((address_space(1))) void*)(vpp + i * 32 * SEQ),
          (__attribute__((address_space(3))) void*)(Vs3 + buf * 8192 + c * 16), 16, 0, 0);
    }
  };

  stage(0, kp, vp);
  kp += KVBLK * EMB;
  vp += KVBLK;
  __syncthreads();

  for (int it = 0; it < SEQ / KVBLK; ++it) {
    const int cur = it & 1;
    if (it + 1 < SEQ / KVBLK) {
      stage(cur ^ 1, kp, vp);
      kp += KVBLK * EMB;
      vp += KVBLK;
    }

    const char* Kb = (const char*)Ks + cur * 8192;
    const char* Vb = (const char*)Vs + cur * 8192;

    // ---- S^T = K . Q^T : st[jh], col q = lq, row j = jh*32 + (reg&3)+8*(reg>>2)+4*lh
    f32x16 st[2] = {};
    __builtin_amdgcn_s_setprio(1);
#pragma unroll
    for (int jh = 0; jh < 2; ++jh) {
      const int row = jh * 32 + lq;
#pragma unroll
      for (int ks = 0; ks < 4; ++ks) {
        bf16x8 kf = *reinterpret_cast<const bf16x8*>(Kb + row * 128 + swz(lq, ks * 32 + lh * 16));
        st[jh] = __builtin_amdgcn_mfma_f32_32x32x16_bf16(kf, qf[ks], st[jh], 0, 0, 0);
      }
    }
    __builtin_amdgcn_s_setprio(0);

    // ---- online softmax (exp2 domain), all in-register ----
    float mx = -1e30f;
#pragma unroll
    for (int jh = 0; jh < 2; ++jh)
#pragma unroll
      for (int r = 0; r < 16; ++r) mx = fmaxf(mx, st[jh][r]);
    mx = pairmax32(mx);

    if (!__all(mx - mrow <= 8.f)) {
      const float mnew = fmaxf(mrow, mx);
      const float al = __builtin_amdgcn_exp2f(mrow - mnew);
      mrow = mnew;
      lrow *= al;
#pragma unroll
      for (int jh = 0; jh < 2; ++jh)
#pragma unroll
        for (int r = 0; r < 16; ++r) o[jh][r] *= al;
    }

    float lsp[2];
#pragma unroll
    for (int jh = 0; jh < 2; ++jh) {
#pragma unroll
      for (int r = 0; r < 16; ++r) st[jh][r] = __builtin_amdgcn_exp2f(st[jh][r] - mrow);
      float a0 = (st[jh][0] + st[jh][1]) + (st[jh][2] + st[jh][3]);
      float a1 = (st[jh][4] + st[jh][5]) + (st[jh][6] + st[jh][7]);
      float a2 = (st[jh][8] + st[jh][9]) + (st[jh][10] + st[jh][11]);
      float a3 = (st[jh][12] + st[jh][13]) + (st[jh][14] + st[jh][15]);
      lsp[jh] = (a0 + a1) + (a2 + a3);
    }
    lrow += pairsum32(lsp[0] + lsp[1]);

    // ---- P^T B-frags in-register: per 16-j step, 4 cvt_pk + 2 permlane ----
    bf16x8 pb[4];
#pragma unroll
    for (int jh = 0; jh < 2; ++jh)
#pragma unroll
      for (int sub = 0; sub < 2; ++sub) {
        int w01, w23, w45, w67;
        asm("v_cvt_pk_bf16_f32 %0, %1, %2" : "=v"(w01) : "v"(st[jh][sub * 8 + 0]), "v"(st[jh][sub * 8 + 1]));
        asm("v_cvt_pk_bf16_f32 %0, %1, %2" : "=v"(w23) : "v"(st[jh][sub * 8 + 2]), "v"(st[jh][sub * 8 + 3]));
        asm("v_cvt_pk_bf16_f32 %0, %1, %2" : "=v"(w45) : "v"(st[jh][sub * 8 + 4]), "v"(st[jh][sub * 8 + 5]));
        asm("v_cvt_pk_bf16_f32 %0, %1, %2" : "=v"(w67) : "v"(st[jh][sub * 8 + 6]), "v"(st[jh][sub * 8 + 7]));
        int d0, d1, d2, d3;
        plswap(w01, w45, d0, d2);
        plswap(w23, w67, d1, d3);
        union { int i[4]; bf16x8 v; } u;
        u.i[0] = d0; u.i[1] = d1; u.i[2] = d2; u.i[3] = d3;
        pb[jh * 2 + sub] = u.v;
      }

    // ---- O^T += Vt . P : o[dh], row d = dh*32 + (reg&3)+8*(reg>>2)+4*lh, col q = lq
    __builtin_amdgcn_s_setprio(1);
#pragma unroll
    for (int dh = 0; dh < 2; ++dh) {
      const int row = dh * 32 + lq;
#pragma unroll
      for (int js = 0; js < 4; ++js) {
        bf16x8 vf = *reinterpret_cast<const bf16x8*>(Vb + row * 128 + swz(lq, js * 32 + lh * 16));
        o[dh] = __builtin_amdgcn_mfma_f32_32x32x16_bf16(vf, pb[js], o[dh], 0, 0, 0);
      }
    }
    __builtin_amdgcn_s_setprio(0);

    __syncthreads();
  }

  // ---- epilogue: lane owns q = lq; d = dh*32 + g*8 + lh*4 + r (4 consecutive) ----
  const float inv = 1.f / lrow;
  const size_t orow = (baseRow + q0 + lq) * EMB + hoff;
#pragma unroll
  for (int dh = 0; dh < 2; ++dh)
#pragma unroll
    for (int g = 0; g < 4; ++g) {
      union { uint2 u2; bf16_t h[4]; } pu;
#pragma unroll
      for (int r = 0; r < 4; ++r) pu.h[r] = __float2bfloat16(o[dh][g * 4 + r] * inv);
      *reinterpret_cast<uint2*>(Oout + orow + dh * 32 + g * 8 + lh * 4) = pu.u2;
    }
}

// ---------------- row LayerNorm (1024 cols), f32 ----------------
__global__ __launch_bounds__(256) void ln_kernel(const float* __restrict__ Y,
                                                 const float* __restrict__ gamma,
                                                 const float* __restrict__ beta,
                                                 float* __restrict__ Out) {
  const int row = blockIdx.x;
  const int tid = threadIdx.x;
  const float4 v = reinterpret_cast<const float4*>(Y + (size_t)row * EMB)[tid];
  float s = v.x + v.y + v.z + v.w;
  float s2 = v.x * v.x + v.y * v.y + v.z * v.z + v.w * v.w;
#pragma unroll
  for (int m = 1; m < 64; m <<= 1) {
    s += __shfl_xor(s, m);
    s2 += __shfl_xor(s2, m);
  }
  __shared__ float ws[4], ws2[4];
  const int w = tid >> 6;
  if ((tid & 63) == 0) { ws[w] = s; ws2[w] = s2; }
  __syncthreads();
  s = ws[0] + ws[1] + ws[2] + ws[3];
  s2 = ws2[0] + ws2[1] + ws2[2] + ws2[3];
  const float mu = s * (1.f / EMB);
  const float var = s2 * (1.f / EMB) - mu * mu;
  const float rstd = rsqrtf(var + 1e-5f);
  const float4 g = reinterpret_cast<const float4*>(gamma)[tid];
  const float4 bt = reinterpret_cast<const float4*>(beta)[tid];
  float4 ov;
  ov.x = (v.x - mu) * rstd * g.x + bt.x;
  ov.y = (v.y - mu) * rstd * g.y + bt.y;
  ov.z = (v.z - mu) * rstd * g.z + bt.z;
  ov.w = (v.w - mu) * rstd * g.w + bt.w;
  reinterpret_cast<float4*>(Out + (size_t)row * EMB)[tid] = ov;
}

// ---------------- launch ----------------
extern "C" void kernel_launch(void* const* d_in, const int* in_sizes, int n_in,
                              void* d_out, int out_size, void* d_ws, size_t ws_size,
                              hipStream_t stream) {
  const float* x = (const float*)d_in[0];
  const float* Wq = (const float*)d_in[1];
  const float* Wk = (const float*)d_in[2];
  const float* Wv = (const float*)d_in[3];
  const float* Wo = (const float*)d_in[4];
  const float* gamma = (const float*)d_in[5];
  const float* beta = (const float*)d_in[6];
  float* out = (float*)d_out;

  char* p = (char*)d_ws;
  const size_t sz_rows_bf = (size_t)NROWS * EMB * sizeof(bf16_t);  // 8 MB
  const size_t sz_w_bf = (size_t)EMB * EMB * sizeof(bf16_t);       // 2 MB
  bf16_t* xb = (bf16_t*)p; p += sz_rows_bf;
  bf16_t* wqb = (bf16_t*)p; p += sz_w_bf;
  bf16_t* wkb = (bf16_t*)p; p += sz_w_bf;
  bf16_t* wvb = (bf16_t*)p; p += sz_w_bf;
  bf16_t* wob = (bf16_t*)p; p += sz_w_bf;
  bf16_t* q = (bf16_t*)p; p += sz_rows_bf;
  bf16_t* k = (bf16_t*)p; p += sz_rows_bf;
  bf16_t* vt = (bf16_t*)p; p += sz_rows_bf;   // [B*H*D][S] = 2048 x 2048
  bf16_t* attn = (bf16_t*)p; p += sz_rows_bf;
  float* y = (float*)q;  // alias: q/k dead after attn_kernel

  const int n4x = NROWS * EMB / 4;
  const int n4w = EMB * EMB / 4;
  cast_f32_to_bf16<<<n4x / 256, 256, 0, stream>>>(x, xb, n4x);
  cast4_w<<<dim3(n4w / 256, 1, 4), 256, 0, stream>>>(Wq, Wk, Wv, Wo, wqb, wkb, wvb, wob, n4w);

  gemm_qkv<<<dim3(EMB / 128, NROWS / 128, 3), 256, 0, stream>>>(xb, wqb, wkb, wvb, q, k, vt);

  attn_kernel<<<dim3(SEQ / 128, NHEAD, BATCH), 256, 0, stream>>>(q, k, vt, attn);

  gemm_out<<<dim3(EMB / 128, NROWS / 128, 1), 256, 0, stream>>>(attn, wob, y, x);

  ln_kernel<<<NROWS, 256, 0, stream>>>(y, gamma, beta, out);
}

// Round 6
// 128.808 us; speedup vs baseline: 1.0907x; 1.0398x over previous
//
#include <hip/hip_runtime.h>
#include <hip/hip_bf16.h>
#include <cstdint>
#include <cstddef>

#define SEQ   2048
#define BATCH 2
#define NROWS 4096          // BATCH*SEQ
#define EMB   1024
#define NHEAD 16
#define HD    64
#define KVBLK 64
#define NT    (SEQ / KVBLK)   // 32 kv tiles

typedef __attribute__((ext_vector_type(8))) short bf16x8;
typedef __attribute__((ext_vector_type(4))) float f32x4;
typedef __attribute__((ext_vector_type(16))) float f32x16;
typedef __attribute__((ext_vector_type(2))) int i32x2;
typedef __hip_bfloat16 bf16_t;

__device__ __forceinline__ int swz(int row, int cb) { return cb ^ ((row & 7) << 4); }

// permlane32_swap: ra = {a_lo, b_lo(from lane-32)}, rb = {a_hi(from lane+32), b_hi}
__device__ __forceinline__ void plswap(int a, int b, int& ra, int& rb) {
#if __has_builtin(__builtin_amdgcn_permlane32_swap)
  i32x2 r = __builtin_amdgcn_permlane32_swap(a, b, false, false);
  ra = r[0]; rb = r[1];
#else
  const int pa = __shfl_xor(a, 32), pb = __shfl_xor(b, 32);
  const bool lo = (threadIdx.x & 63) < 32;
  ra = lo ? a : pb;
  rb = lo ? pa : b;
#endif
}
__device__ __forceinline__ float pairmax32(float v) {
  int r0, r1;
  plswap(__float_as_int(v), __float_as_int(v), r0, r1);
  return fmaxf(__int_as_float(r0), __int_as_float(r1));
}
__device__ __forceinline__ float pairsum32(float v) {
  int r0, r1;
  plswap(__float_as_int(v), __float_as_int(v), r0, r1);
  return __int_as_float(r0) + __int_as_float(r1);
}

// ---------------- casts f32 -> bf16 (vectorized) ----------------
__global__ __launch_bounds__(256) void cast_f32_to_bf16(const float* __restrict__ in,
                                                        bf16_t* __restrict__ out, int n4) {
  int i = blockIdx.x * 256 + threadIdx.x;
  if (i >= n4) return;
  float4 v = reinterpret_cast<const float4*>(in)[i];
  union { ushort4 u; bf16_t h[4]; } o;
  o.h[0] = __float2bfloat16(v.x);
  o.h[1] = __float2bfloat16(v.y);
  o.h[2] = __float2bfloat16(v.z);
  o.h[3] = __float2bfloat16(v.w);
  reinterpret_cast<ushort4*>(out)[i] = o.u;
}

__global__ __launch_bounds__(256) void cast4_w(const float* __restrict__ a,
                                               const float* __restrict__ b,
                                               const float* __restrict__ c,
                                               const float* __restrict__ d,
                                               bf16_t* __restrict__ oa, bf16_t* __restrict__ ob,
                                               bf16_t* __restrict__ oc, bf16_t* __restrict__ od,
                                               int n4) {
  const int z = blockIdx.z;
  const float* in = (z == 0) ? a : (z == 1) ? b : (z == 2) ? c : d;
  bf16_t* out = (z == 0) ? oa : (z == 1) ? ob : (z == 2) ? oc : od;
  int i = blockIdx.x * 256 + threadIdx.x;
  if (i >= n4) return;
  float4 v = reinterpret_cast<const float4*>(in)[i];
  union { ushort4 u; bf16_t h[4]; } o;
  o.h[0] = __float2bfloat16(v.x);
  o.h[1] = __float2bfloat16(v.y);
  o.h[2] = __float2bfloat16(v.z);
  o.h[3] = __float2bfloat16(v.w);
  reinterpret_cast<ushort4*>(out)[i] = o.u;
}

// ---------------- 128x128 bf16 MFMA GEMM (m97 structure) ----------------
template <int MODE>
__device__ __forceinline__ void gemm128_body(const bf16_t* __restrict__ A,
                                             const bf16_t* __restrict__ W,
                                             bf16_t* __restrict__ Ob,
                                             float* __restrict__ Of,
                                             const float* __restrict__ Res) {
  __shared__ __align__(16) bf16_t As[128 * 32];
  __shared__ __align__(16) bf16_t Bs[128 * 32];
  const int tid = threadIdx.x;
  const int lane = tid & 63;
  const int wv = tid >> 6;
  const int wm = wv >> 1, wn = wv & 1;          // 2x2 waves, each owns 64x64
  const int brow = blockIdx.y * 128;
  const int bcol = blockIdx.x * 128;
  const int lr = lane & 15, lg = lane >> 4;

  f32x4 acc[4][4] = {};

  auto* As3 = (__attribute__((address_space(3))) char*)As;
  auto* Bs3 = (__attribute__((address_space(3))) char*)Bs;

  for (int k0 = 0; k0 < EMB; k0 += 32) {
    __syncthreads();
#pragma unroll
    for (int i = 0; i < 2; ++i) {
      const int chunk = i * 256 + tid;          // 0..511, 16B each
      const int row = chunk >> 2;               // tile row 0..127
      const int kc = (chunk & 3) * 8;           // k element 0/8/16/24
      const bf16_t* ga = A + (size_t)(brow + row) * EMB + k0 + kc;
      const bf16_t* gb = W + (size_t)(bcol + row) * EMB + k0 + kc;
      __builtin_amdgcn_global_load_lds((const __attribute__((address_space(1))) void*)ga,
                                       (__attribute__((address_space(3))) void*)(As3 + chunk * 16),
                                       16, 0, 0);
      __builtin_amdgcn_global_load_lds((const __attribute__((address_space(1))) void*)gb,
                                       (__attribute__((address_space(3))) void*)(Bs3 + chunk * 16),
                                       16, 0, 0);
    }
    __syncthreads();

    bf16x8 af[4], bfr[4];
#pragma unroll
    for (int m = 0; m < 4; ++m)
      af[m] = *reinterpret_cast<const bf16x8*>(&As[(wm * 64 + m * 16 + lr) * 32 + lg * 8]);
#pragma unroll
    for (int n = 0; n < 4; ++n)
      bfr[n] = *reinterpret_cast<const bf16x8*>(&Bs[(wn * 64 + n * 16 + lr) * 32 + lg * 8]);
#pragma unroll
    for (int m = 0; m < 4; ++m)
#pragma unroll
      for (int n = 0; n < 4; ++n)
        acc[m][n] = __builtin_amdgcn_mfma_f32_16x16x32_bf16(af[m], bfr[n], acc[m][n], 0, 0, 0);
  }

  const int r0 = brow + wm * 64;
  const int c0 = bcol + wn * 64;
#pragma unroll
  for (int m = 0; m < 4; ++m)
#pragma unroll
    for (int n = 0; n < 4; ++n) {
      if (MODE == 2) {
        const int row0 = r0 + m * 16 + lg * 4;
        const int col = c0 + n * 16 + lr;
        const size_t vt_row = (size_t)(row0 >> 11) * 1024 + col;
        const int s = row0 & 2047;
        union { uint2 u2; bf16_t h[4]; } pu;
#pragma unroll
        for (int r = 0; r < 4; ++r) pu.h[r] = __float2bfloat16(acc[m][n][r]);
        *reinterpret_cast<uint2*>(Ob + vt_row * SEQ + s) = pu.u2;
      } else {
#pragma unroll
        for (int r = 0; r < 4; ++r) {
          const int row = r0 + m * 16 + lg * 4 + r;
          const int col = c0 + n * 16 + lr;
          const size_t idx = (size_t)row * EMB + col;
          if (MODE == 0) Ob[idx] = __float2bfloat16(acc[m][n][r]);
          else Of[idx] = acc[m][n][r] + Res[idx];
        }
      }
    }
}

__global__ __launch_bounds__(256) void gemm_qkv(const bf16_t* __restrict__ X,
                                                const bf16_t* __restrict__ Wq,
                                                const bf16_t* __restrict__ Wk,
                                                const bf16_t* __restrict__ Wv,
                                                bf16_t* __restrict__ Q,
                                                bf16_t* __restrict__ K,
                                                bf16_t* __restrict__ Vt) {
  if (blockIdx.z == 0)      gemm128_body<0>(X, Wq, Q, nullptr, nullptr);
  else if (blockIdx.z == 1) gemm128_body<0>(X, Wk, K, nullptr, nullptr);
  else                      gemm128_body<2>(X, Wv, Vt, nullptr, nullptr);
}

__global__ __launch_bounds__(256) void gemm_out(const bf16_t* __restrict__ Attn,
                                                const bf16_t* __restrict__ Wo,
                                                float* __restrict__ Y,
                                                const float* __restrict__ X) {
  gemm128_body<1>(Attn, Wo, nullptr, Y, X);
}

// ---------------- flash attention: 32x32 MFMA, in-register P, pipelined ----
// 4 waves x 32 q-rows; swapped QK^T; softmax/P fully in-register.
// In-wave pipeline: QK(t+1) issued right after barrier, softmax+PV(t) overlap
// the MFMA chain. 3-buffer LDS rotation (mod-3 distance-2 hazard-free).
__global__ __launch_bounds__(256) void attn_kernel(const bf16_t* __restrict__ Q,
                                                   const bf16_t* __restrict__ K,
                                                   const bf16_t* __restrict__ Vt,
                                                   bf16_t* __restrict__ Oout) {
  __shared__ __align__(16) bf16_t Ks[3][KVBLK * 64];   // swizzled [j][d], 8KB each
  __shared__ __align__(16) bf16_t Vs[3][KVBLK * 64];   // swizzled [d][j], 8KB each

  const int tid = threadIdx.x;
  const int lane = tid & 63;
  const int wv = tid >> 6;
  const int lq = lane & 31;     // q column / A row
  const int lh = lane >> 5;     // k-group half

  // XCD-aware bijective swizzle over 512 blocks
  const int f = blockIdx.x + 16 * blockIdx.y + 256 * blockIdx.z;
  const int w = (f & 7) * 64 + (f >> 3);
  const int qb = w & 15;
  const int h = (w >> 4) & 15;
  const int b = w >> 8;

  const size_t baseRow = (size_t)b * SEQ;
  const int hoff = h * HD;
  const int q0 = qb * 128 + wv * 32;

  // Q B-frags: col q = lq, d = ks*16 + lh*8 + e; pre-scaled by 0.125*log2(e)
  const float qscale = 0.125f * 1.44269504f;
  bf16x8 qf[4];
#pragma unroll
  for (int ks = 0; ks < 4; ++ks) {
    bf16x8 t = *reinterpret_cast<const bf16x8*>(
        &Q[(baseRow + q0 + lq) * EMB + hoff + ks * 16 + lh * 8]);
    union { bf16x8 v; bf16_t h[8]; } u;
    u.v = t;
#pragma unroll
    for (int e = 0; e < 8; ++e)
      u.h[e] = __float2bfloat16(__bfloat162float(u.h[e]) * qscale);
    qf[ks] = u.v;
  }

  f32x16 o0 = {}, o1 = {};
  float mrow = -1e30f, lrow = 0.f;

  auto* Ks3 = (__attribute__((address_space(3))) char*)&Ks[0][0];
  auto* Vs3 = (__attribute__((address_space(3))) char*)&Vs[0][0];

  // hoisted per-thread staging pointers (row = tid>>3; same row&7 both chunks)
  const int srow = tid >> 3;
  const int scb = swz(srow, (tid & 7) * 16) >> 1;
  const bf16_t* kp = K + (baseRow + srow) * EMB + hoff + scb;
  const bf16_t* vp = Vt + ((size_t)(b * 1024 + hoff) + srow) * SEQ + scb;

  auto stage = [&](int buf) {
#pragma unroll
    for (int i = 0; i < 2; ++i) {
      const int c = i * 256 + tid;
      __builtin_amdgcn_global_load_lds(
          (const __attribute__((address_space(1))) void*)(kp + i * 32 * EMB),
          (__attribute__((address_space(3))) void*)(Ks3 + buf * 8192 + c * 16), 16, 0, 0);
      __builtin_amdgcn_global_load_lds(
          (const __attribute__((address_space(1))) void*)(vp + i * 32 * SEQ),
          (__attribute__((address_space(3))) void*)(Vs3 + buf * 8192 + c * 16), 16, 0, 0);
    }
    kp += KVBLK * EMB;
    vp += KVBLK;
  };

  // QK^T into named score regs: col q = lq, row j = jh*32 + (reg&3)+8*(reg>>2)+4*lh
  auto QKT = [&](int buf, f32x16& s0, f32x16& s1) {
    const char* Kb = (const char*)Ks + buf * 8192;
    s0 = (f32x16){};
    s1 = (f32x16){};
    __builtin_amdgcn_s_setprio(1);
#pragma unroll
    for (int ks = 0; ks < 4; ++ks) {
      bf16x8 kf0 = *reinterpret_cast<const bf16x8*>(Kb + lq * 128 + swz(lq, ks * 32 + lh * 16));
      s0 = __builtin_amdgcn_mfma_f32_32x32x16_bf16(kf0, qf[ks], s0, 0, 0, 0);
    }
#pragma unroll
    for (int ks = 0; ks < 4; ++ks) {
      bf16x8 kf1 = *reinterpret_cast<const bf16x8*>(Kb + (32 + lq) * 128 + swz(lq, ks * 32 + lh * 16));
      s1 = __builtin_amdgcn_mfma_f32_32x32x16_bf16(kf1, qf[ks], s1, 0, 0, 0);
    }
    __builtin_amdgcn_s_setprio(0);
  };

  // softmax (exp2 domain, in-register) + P b-frags + PV accumulate
  auto FIN = [&](f32x16& st0, f32x16& st1, int buf) {
    const char* Vb = (const char*)Vs + buf * 8192;
    float mx = -1e30f;
#pragma unroll
    for (int r = 0; r < 16; ++r) mx = fmaxf(mx, st0[r]);
#pragma unroll
    for (int r = 0; r < 16; ++r) mx = fmaxf(mx, st1[r]);
    mx = pairmax32(mx);

    if (!__all(mx - mrow <= 8.f)) {
      const float mnew = fmaxf(mrow, mx);
      const float al = __builtin_amdgcn_exp2f(mrow - mnew);
      mrow = mnew;
      lrow *= al;
#pragma unroll
      for (int r = 0; r < 16; ++r) o0[r] *= al;
#pragma unroll
      for (int r = 0; r < 16; ++r) o1[r] *= al;
    }

#pragma unroll
    for (int r = 0; r < 16; ++r) st0[r] = __builtin_amdgcn_exp2f(st0[r] - mrow);
#pragma unroll
    for (int r = 0; r < 16; ++r) st1[r] = __builtin_amdgcn_exp2f(st1[r] - mrow);
    {
      float a0 = (st0[0] + st0[1]) + (st0[2] + st0[3]);
      float a1 = (st0[4] + st0[5]) + (st0[6] + st0[7]);
      float a2 = (st0[8] + st0[9]) + (st0[10] + st0[11]);
      float a3 = (st0[12] + st0[13]) + (st0[14] + st0[15]);
      float b0 = (st1[0] + st1[1]) + (st1[2] + st1[3]);
      float b1 = (st1[4] + st1[5]) + (st1[6] + st1[7]);
      float b2 = (st1[8] + st1[9]) + (st1[10] + st1[11]);
      float b3 = (st1[12] + st1[13]) + (st1[14] + st1[15]);
      lrow += pairsum32(((a0 + a1) + (a2 + a3)) + ((b0 + b1) + (b2 + b3)));
    }

    // P^T B-frags in-register: per 16-j step, 4 cvt_pk + 2 permlane
    bf16x8 pb[4];
#pragma unroll
    for (int jh = 0; jh < 2; ++jh)
#pragma unroll
      for (int sub = 0; sub < 2; ++sub) {
        const f32x16& s = jh ? st1 : st0;
        int w01, w23, w45, w67;
        asm("v_cvt_pk_bf16_f32 %0, %1, %2" : "=v"(w01) : "v"(s[sub * 8 + 0]), "v"(s[sub * 8 + 1]));
        asm("v_cvt_pk_bf16_f32 %0, %1, %2" : "=v"(w23) : "v"(s[sub * 8 + 2]), "v"(s[sub * 8 + 3]));
        asm("v_cvt_pk_bf16_f32 %0, %1, %2" : "=v"(w45) : "v"(s[sub * 8 + 4]), "v"(s[sub * 8 + 5]));
        asm("v_cvt_pk_bf16_f32 %0, %1, %2" : "=v"(w67) : "v"(s[sub * 8 + 6]), "v"(s[sub * 8 + 7]));
        int d0, d1, d2, d3;
        plswap(w01, w45, d0, d2);
        plswap(w23, w67, d1, d3);
        union { int i[4]; bf16x8 v; } u;
        u.i[0] = d0; u.i[1] = d1; u.i[2] = d2; u.i[3] = d3;
        pb[jh * 2 + sub] = u.v;
      }

    __builtin_amdgcn_s_setprio(1);
#pragma unroll
    for (int js = 0; js < 4; ++js) {
      bf16x8 vf0 = *reinterpret_cast<const bf16x8*>(Vb + lq * 128 + swz(lq, js * 32 + lh * 16));
      o0 = __builtin_amdgcn_mfma_f32_32x32x16_bf16(vf0, pb[js], o0, 0, 0, 0);
    }
#pragma unroll
    for (int js = 0; js < 4; ++js) {
      bf16x8 vf1 = *reinterpret_cast<const bf16x8*>(Vb + (32 + lq) * 128 + swz(lq, js * 32 + lh * 16));
      o1 = __builtin_amdgcn_mfma_f32_32x32x16_bf16(vf1, pb[js], o1, 0, 0, 0);
    }
    __builtin_amdgcn_s_setprio(0);
  };

  f32x16 sA0, sA1, sB0, sB1;

  // prologue: S(0); B; S(1); QK(0)->A
  stage(0);
  __syncthreads();
  stage(1);
  QKT(0, sA0, sA1);

  // steady state, hand-unrolled x2 for static st naming.
  // per phase: B; S(t+1); QK(t)->other; FIN(t-1) from cur.
  for (int t = 1; t + 1 < NT; t += 2) {
    // phase A: tile t -> B regs; finish tile t-1 (A regs)
    __syncthreads();
    stage((t + 1) % 3);
    QKT(t % 3, sB0, sB1);
    FIN(sA0, sA1, (t - 1) % 3);
    // phase B: tile t+1 -> A regs; finish tile t (B regs)
    __syncthreads();
    if (t + 2 < NT) stage((t + 2) % 3);
    QKT((t + 1) % 3, sA0, sA1);
    FIN(sB0, sB1, t % 3);
  }
  // t == NT-1 (31) remaining: QK(31)->B; FIN(30)=A; FIN(31)=B
  __syncthreads();
  QKT((NT - 1) % 3, sB0, sB1);
  FIN(sA0, sA1, (NT - 2) % 3);
  FIN(sB0, sB1, (NT - 1) % 3);

  // ---- epilogue: lane owns q = lq; d = dh*32 + g*8 + lh*4 + r (4 consecutive) ----
  const float inv = 1.f / lrow;
  const size_t orow = (baseRow + q0 + lq) * EMB + hoff;
#pragma unroll
  for (int g = 0; g < 4; ++g) {
    union { uint2 u2; bf16_t h[4]; } pu;
#pragma unroll
    for (int r = 0; r < 4; ++r) pu.h[r] = __float2bfloat16(o0[g * 4 + r] * inv);
    *reinterpret_cast<uint2*>(Oout + orow + g * 8 + lh * 4) = pu.u2;
  }
#pragma unroll
  for (int g = 0; g < 4; ++g) {
    union { uint2 u2; bf16_t h[4]; } pu;
#pragma unroll
    for (int r = 0; r < 4; ++r) pu.h[r] = __float2bfloat16(o1[g * 4 + r] * inv);
    *reinterpret_cast<uint2*>(Oout + orow + 32 + g * 8 + lh * 4) = pu.u2;
  }
}

// ---------------- row LayerNorm (1024 cols), f32 ----------------
__global__ __launch_bounds__(256) void ln_kernel(const float* __restrict__ Y,
                                                 const float* __restrict__ gamma,
                                                 const float* __restrict__ beta,
                                                 float* __restrict__ Out) {
  const int row = blockIdx.x;
  const int tid = threadIdx.x;
  const float4 v = reinterpret_cast<const float4*>(Y + (size_t)row * EMB)[tid];
  float s = v.x + v.y + v.z + v.w;
  float s2 = v.x * v.x + v.y * v.y + v.z * v.z + v.w * v.w;
#pragma unroll
  for (int m = 1; m < 64; m <<= 1) {
    s += __shfl_xor(s, m);
    s2 += __shfl_xor(s2, m);
  }
  __shared__ float ws[4], ws2[4];
  const int w = tid >> 6;
  if ((tid & 63) == 0) { ws[w] = s; ws2[w] = s2; }
  __syncthreads();
  s = ws[0] + ws[1] + ws[2] + ws[3];
  s2 = ws2[0] + ws2[1] + ws2[2] + ws2[3];
  const float mu = s * (1.f / EMB);
  const float var = s2 * (1.f / EMB) - mu * mu;
  const float rstd = rsqrtf(var + 1e-5f);
  const float4 g = reinterpret_cast<const float4*>(gamma)[tid];
  const float4 bt = reinterpret_cast<const float4*>(beta)[tid];
  float4 ov;
  ov.x = (v.x - mu) * rstd * g.x + bt.x;
  ov.y = (v.y - mu) * rstd * g.y + bt.y;
  ov.z = (v.z - mu) * rstd * g.z + bt.z;
  ov.w = (v.w - mu) * rstd * g.w + bt.w;
  reinterpret_cast<float4*>(Out + (size_t)row * EMB)[tid] = ov;
}

// ---------------- launch ----------------
extern "C" void kernel_launch(void* const* d_in, const int* in_sizes, int n_in,
                              void* d_out, int out_size, void* d_ws, size_t ws_size,
                              hipStream_t stream) {
  const float* x = (const float*)d_in[0];
  const float* Wq = (const float*)d_in[1];
  const float* Wk = (const float*)d_in[2];
  const float* Wv = (const float*)d_in[3];
  const float* Wo = (const float*)d_in[4];
  const float* gamma = (const float*)d_in[5];
  const float* beta = (const float*)d_in[6];
  float* out = (float*)d_out;

  char* p = (char*)d_ws;
  const size_t sz_rows_bf = (size_t)NROWS * EMB * sizeof(bf16_t);  // 8 MB
  const size_t sz_w_bf = (size_t)EMB * EMB * sizeof(bf16_t);       // 2 MB
  bf16_t* xb = (bf16_t*)p; p += sz_rows_bf;
  bf16_t* wqb = (bf16_t*)p; p += sz_w_bf;
  bf16_t* wkb = (bf16_t*)p; p += sz_w_bf;
  bf16_t* wvb = (bf16_t*)p; p += sz_w_bf;
  bf16_t* wob = (bf16_t*)p; p += sz_w_bf;
  bf16_t* q = (bf16_t*)p; p += sz_rows_bf;
  bf16_t* k = (bf16_t*)p; p += sz_rows_bf;
  bf16_t* vt = (bf16_t*)p; p += sz_rows_bf;   // [B*H*D][S] = 2048 x 2048
  bf16_t* attn = (bf16_t*)p; p += sz_rows_bf;
  float* y = (float*)q;  // alias: q/k dead after attn_kernel

  const int n4x = NROWS * EMB / 4;
  const int n4w = EMB * EMB / 4;
  cast_f32_to_bf16<<<n4x / 256, 256, 0, stream>>>(x, xb, n4x);
  cast4_w<<<dim3(n4w / 256, 1, 4), 256, 0, stream>>>(Wq, Wk, Wv, Wo, wqb, wkb, wvb, wob, n4w);

  gemm_qkv<<<dim3(EMB / 128, NROWS / 128, 3), 256, 0, stream>>>(xb, wqb, wkb, wvb, q, k, vt);

  attn_kernel<<<dim3(SEQ / 128, NHEAD, BATCH), 256, 0, stream>>>(q, k, vt, attn);

  gemm_out<<<dim3(EMB / 128, NROWS / 128, 1), 256, 0, stream>>>(attn, wob, y, x);

  ln_kernel<<<NROWS, 256, 0, stream>>>(y, gamma, beta, out);
}